// Round 17
// baseline (203.319 us; speedup 1.0000x reference)
//
#include <hip/hip_runtime.h>
#include <hip/hip_bf16.h>

#define NF 128
#define EPB 4096      // edges per binA role block (int2 staging, 32 KB)
#define EPB2 8192     // edges per binA2 role block (int staging, 32 KB)
#define CAP 6144      // per-bucket region capacity (mean 4096, +32 sigma)

typedef __attribute__((ext_vector_type(8))) short short8;   // 8 bf16 (4 VGPRs)
typedef __attribute__((ext_vector_type(4))) float f32x4;    // MFMA acc
typedef __attribute__((ext_vector_type(4))) unsigned int uint4e;  // nt-load capable

// ---------------- init (1 block) ----------------
__global__ void k_init(int* __restrict__ bucketCnt, int* __restrict__ bucketCntS,
                       int* __restrict__ rowoff, int N, int E) {
  int i = threadIdx.x;
  for (int k = i; k < 512; k += 256) { bucketCnt[k] = 0; bucketCntS[k] = 0; }
  if (i == 0) rowoff[N] = E;
}

// ---------------- frontA: binA | binA2 | W1->bf16^T convert ----------------
__global__ __launch_bounds__(256) void k_frontA(const int* __restrict__ src,
                                                const int* __restrict__ dst,
                                                const float* __restrict__ W1,
                                                int* __restrict__ bucketCnt,
                                                int* __restrict__ bucketCntS,
                                                int2* __restrict__ region,
                                                int* __restrict__ regionS,
                                                unsigned short* __restrict__ WbT,
                                                int E, int B1, int B2) {
  __shared__ __align__(16) char smem_raw[42240];  // 9216 ctl + 32768 staging
  int* cnt   = (int*)smem_raw;
  int* scanv = cnt + 512;
  int* cur   = scanv + 512;
  int* gb    = cur + 512;
  int* s1    = gb + 512;
  void* stv  = (void*)(smem_raw + 9216 + 256);  // 16B-aligned staging
  int tid = threadIdx.x;
  int b = blockIdx.x;

  if (b >= B1 + B2) {
    // ---- W-convert role (16 blocks): WbT[n][k] = bf16(W1[k][n]) ----
    int u = (b - B1 - B2) * 256 + tid;   // 0..4095 ushort4 units
    int n  = u >> 5;
    int k4 = (u & 31) << 2;
    ushort4 o;
    __hip_bfloat16 h0 = __float2bfloat16(W1[(k4 + 0) * NF + n]);
    __hip_bfloat16 h1 = __float2bfloat16(W1[(k4 + 1) * NF + n]);
    __hip_bfloat16 h2 = __float2bfloat16(W1[(k4 + 2) * NF + n]);
    __hip_bfloat16 h3 = __float2bfloat16(W1[(k4 + 3) * NF + n]);
    o.x = *(unsigned short*)&h0;
    o.y = *(unsigned short*)&h1;
    o.z = *(unsigned short*)&h2;
    o.w = *(unsigned short*)&h3;
    *(ushort4*)&WbT[n * NF + k4] = o;
    return;
  }

  if (b < B1) {
    // ---- binA role: bin (dst,src) pairs into 256-node buckets ----
    int2* st = (int2*)stv;
    int b0 = b * EPB;
    int n = E - b0; if (n > EPB) n = EPB;

    for (int k = tid; k < 512; k += 256) cnt[k] = 0;
    __syncthreads();
    for (int k = tid; k < n; k += 256) atomicAdd(&cnt[dst[b0 + k] >> 8], 1);
    __syncthreads();

    int c0 = cnt[2 * tid], c1 = cnt[2 * tid + 1];
    s1[tid] = c0 + c1;
    __syncthreads();
    for (int off = 1; off < 256; off <<= 1) {
      int v = (tid >= off) ? s1[tid - off] : 0;
      __syncthreads();
      s1[tid] += v;
      __syncthreads();
    }
    int excl = tid ? s1[tid - 1] : 0;
    scanv[2 * tid] = excl;
    scanv[2 * tid + 1] = excl + c0;
    cur[2 * tid] = excl;
    cur[2 * tid + 1] = excl + c0;
    gb[2 * tid]     = c0 ? atomicAdd(&bucketCnt[2 * tid], c0) : 0;
    gb[2 * tid + 1] = c1 ? atomicAdd(&bucketCnt[2 * tid + 1], c1) : 0;
    __syncthreads();

    for (int k = tid; k < n; k += 256) {
      int d = dst[b0 + k], s = src[b0 + k];
      int p = atomicAdd(&cur[d >> 8], 1);
      st[p] = make_int2(d, s);
    }
    __syncthreads();
    for (int k = tid; k < n; k += 256) {
      int2 e = st[k];
      int bk = e.x >> 8;
      int gp = gb[bk] + (k - scanv[bk]);
      if (gp < CAP) region[(size_t)bk * CAP + gp] = e;
    }
    return;
  }

  // ---- binA2 role: bin bare src values (out-degree) ----
  int* st = (int*)stv;
  int b0 = (b - B1) * EPB2;
  int n = E - b0; if (n > EPB2) n = EPB2;

  for (int k = tid; k < 512; k += 256) cnt[k] = 0;
  __syncthreads();
  for (int k = tid; k < n; k += 256) atomicAdd(&cnt[src[b0 + k] >> 8], 1);
  __syncthreads();

  int c0 = cnt[2 * tid], c1 = cnt[2 * tid + 1];
  s1[tid] = c0 + c1;
  __syncthreads();
  for (int off = 1; off < 256; off <<= 1) {
    int v = (tid >= off) ? s1[tid - off] : 0;
    __syncthreads();
    s1[tid] += v;
    __syncthreads();
  }
  int excl = tid ? s1[tid - 1] : 0;
  scanv[2 * tid] = excl;
  scanv[2 * tid + 1] = excl + c0;
  cur[2 * tid] = excl;
  cur[2 * tid + 1] = excl + c0;
  gb[2 * tid]     = c0 ? atomicAdd(&bucketCntS[2 * tid], c0) : 0;
  gb[2 * tid + 1] = c1 ? atomicAdd(&bucketCntS[2 * tid + 1], c1) : 0;
  __syncthreads();

  for (int k = tid; k < n; k += 256) {
    int s = src[b0 + k];
    int p = atomicAdd(&cur[s >> 8], 1);
    st[p] = s;
  }
  __syncthreads();
  for (int k = tid; k < n; k += 256) {
    int s = st[k];
    int bk = s >> 8;
    int gp = gb[bk] + (k - scanv[bk]);
    if (gp < CAP) regionS[(size_t)bk * CAP + gp] = s;
  }
}

// ---------------- mid: binB | binB2 | MFMA gemm1 (bf16 W pre-staged) ----------------
// LDS (gemm role): Wb bf16 [128][136] (34816 B), Xb bf16 [64][136] (17408 B)
__global__ __launch_bounds__(256) void k_mid(const float* __restrict__ x,
                                             const unsigned short* __restrict__ WbT,
                                             const int2* __restrict__ region,
                                             const int* __restrict__ bucketCnt,
                                             const int* __restrict__ regionS,
                                             const int* __restrict__ bucketCntS,
                                             int* __restrict__ csr,
                                             int* __restrict__ rowoff,
                                             float* __restrict__ invI,
                                             float* __restrict__ invO,
                                             unsigned short* __restrict__ xw,
                                             int N, int NB) {
  __shared__ __align__(16) char smem_raw[52224];
  int tid = threadIdx.x;
  int blk = blockIdx.x;

  if (blk < NB) {
    // ---- binB role: counting sort -> csr + rowoff + invI ----
    int* s1   = (int*)smem_raw;
    int* hist = s1 + 256;
    int* incl = hist + 256;
    int* cur  = incl + 256;
    int b = blk;
    int c0 = (2 * tid < NB) ? bucketCnt[2 * tid] : 0;
    int c1 = (2 * tid + 1 < NB) ? bucketCnt[2 * tid + 1] : 0;
    s1[tid] = c0 + c1;
    __syncthreads();
    for (int off = 1; off < 256; off <<= 1) {
      int v = (tid >= off) ? s1[tid - off] : 0;
      __syncthreads();
      s1[tid] += v;
      __syncthreads();
    }
    int t = b >> 1;
    int csrBase = t ? s1[t - 1] : 0;
    if (b & 1) csrBase += bucketCnt[b & ~1];

    int base = b << 8;
    int nN = N - base; if (nN > 256) nN = 256;
    int cntb = bucketCnt[b]; if (cntb > CAP) cntb = CAP;
    const int2* reg = region + (size_t)b * CAP;

    hist[tid] = 0;
    __syncthreads();
    for (int k = tid; k < cntb; k += 256) atomicAdd(&hist[reg[k].x - base], 1);
    __syncthreads();
    int h = hist[tid];
    incl[tid] = h;
    __syncthreads();
    for (int off = 1; off < 256; off <<= 1) {
      int v = (tid >= off) ? incl[tid - off] : 0;
      __syncthreads();
      incl[tid] += v;
      __syncthreads();
    }
    int startt = incl[tid] - h;  // exclusive
    if (tid < nN) {
      rowoff[base + tid] = csrBase + startt;
      invI[base + tid] = rsqrtf(fmaxf((float)h, 1.0f));
    }
    cur[tid] = startt;
    __syncthreads();
    for (int k = tid; k < cntb; k += 256) {
      int2 e = reg[k];
      int p = atomicAdd(&cur[e.x - base], 1);
      csr[csrBase + p] = e.y;
    }
    return;
  }

  if (blk < 2 * NB) {
    // ---- binB2 role: src histogram -> invO ----
    int* hist = (int*)smem_raw;
    int b = blk - NB;
    int base = b << 8;
    int cntb = bucketCntS[b]; if (cntb > CAP) cntb = CAP;
    const int* reg = regionS + (size_t)b * CAP;
    hist[tid] = 0;
    __syncthreads();
    for (int k = tid; k < cntb; k += 256) atomicAdd(&hist[reg[k] - base], 1);
    __syncthreads();
    if (base + tid < N) invO[base + tid] = rsqrtf(fmaxf((float)hist[tid], 1.0f));
    return;
  }

  // ---- gemm role (MFMA): xw[64 rows] = bf16( x @ W1 ) ----
  unsigned short* Wb = (unsigned short*)smem_raw;   // [128][136]
  unsigned short* Xb = Wb + 128 * 136;              // [64][136]
  int idx = blk - 2 * NB;
  int rowbase = idx * 64;

  // stage x tile first (cold long-latency stream): Xb[r][k] = bf16(x[rowbase+r][k])
  for (int t = tid; t < 64 * 32; t += 256) {
    int r = t >> 5, k4 = (t & 31) << 2;
    int row = rowbase + r; if (row >= N) row = N - 1;
    float4 v = *(const float4*)&x[(size_t)row * NF + k4];
    __hip_bfloat16 h0 = __float2bfloat16(v.x);
    __hip_bfloat16 h1 = __float2bfloat16(v.y);
    __hip_bfloat16 h2 = __float2bfloat16(v.z);
    __hip_bfloat16 h3 = __float2bfloat16(v.w);
    ushort4 u;
    u.x = *(unsigned short*)&h0;
    u.y = *(unsigned short*)&h1;
    u.z = *(unsigned short*)&h2;
    u.w = *(unsigned short*)&h3;
    *(ushort4*)&Xb[r * 136 + k4] = u;
  }
  // stage pre-converted W^T: straight 16B copies (L2-hot 32 KB)
  for (int t = tid; t < 128 * 16; t += 256) {
    int n = t >> 4, k8 = (t & 15) << 3;
    short8 v = *(const short8*)&WbT[n * NF + k8];
    *(short8*)&Wb[n * 136 + k8] = v;
  }
  __syncthreads();

  int w    = tid >> 6;   // wave 0..3 -> rows w*16..w*16+15
  int lane = tid & 63;
  int r16  = lane & 15;
  int kg   = lane >> 4;  // 0..3

  short8 afrag[4];
#pragma unroll
  for (int kk = 0; kk < 4; ++kk) {
    afrag[kk] = *(const short8*)&Xb[(w * 16 + r16) * 136 + kg * 8 + kk * 32];
  }

#pragma unroll
  for (int ct = 0; ct < 8; ++ct) {
    f32x4 acc = {0.f, 0.f, 0.f, 0.f};
#pragma unroll
    for (int kk = 0; kk < 4; ++kk) {
      short8 bfrag = *(const short8*)&Wb[(ct * 16 + r16) * 136 + kg * 8 + kk * 32];
      acc = __builtin_amdgcn_mfma_f32_16x16x32_bf16(afrag[kk], bfrag, acc, 0, 0, 0);
    }
#pragma unroll
    for (int reg = 0; reg < 4; ++reg) {
      int row = rowbase + w * 16 + kg * 4 + reg;
      if (row < N) {
        __hip_bfloat16 hb = __float2bfloat16(acc[reg]);
        xw[(size_t)row * NF + ct * 16 + r16] = *(unsigned short*)&hb;
      }
    }
  }
}

// ---------------- fused gather + layer-2 projection (nt uint4 loads) ----------------
__global__ __launch_bounds__(256) void k_gather_proj(const unsigned short* __restrict__ xw,
                                                     const int* __restrict__ rowoff,
                                                     const int* __restrict__ csr,
                                                     const float* __restrict__ invI,
                                                     const float* __restrict__ invO,
                                                     const float* __restrict__ b1,
                                                     const float* __restrict__ W2,
                                                     float* __restrict__ h2, int N) {
  int i    = blockIdx.x * 4 + (threadIdx.x >> 6);
  int lane = threadIdx.x & 63;
  int grp  = lane >> 4;   // 0..3
  int sl   = lane & 15;
  if (i >= N) return;
  int jb = rowoff[i];
  int je = rowoff[i + 1];
  const uint4e* xwq = (const uint4e*)xw;  // 16 uint4e per row
  float a0 = 0.f, a1 = 0.f, a2 = 0.f, a3 = 0.f;
  float a4 = 0.f, a5 = 0.f, a6 = 0.f, a7 = 0.f;

#define ACC8(v, o)                                                         \
  do {                                                                     \
    a0 = fmaf(__uint_as_float(((v).x & 0xffffu) << 16), (o), a0);          \
    a1 = fmaf(__uint_as_float((v).x & 0xffff0000u), (o), a1);              \
    a2 = fmaf(__uint_as_float(((v).y & 0xffffu) << 16), (o), a2);          \
    a3 = fmaf(__uint_as_float((v).y & 0xffff0000u), (o), a3);              \
    a4 = fmaf(__uint_as_float(((v).z & 0xffffu) << 16), (o), a4);          \
    a5 = fmaf(__uint_as_float((v).z & 0xffff0000u), (o), a5);              \
    a6 = fmaf(__uint_as_float(((v).w & 0xffffu) << 16), (o), a6);          \
    a7 = fmaf(__uint_as_float((v).w & 0xffff0000u), (o), a7);              \
  } while (0)

  int j = jb;
  for (; j + 8 <= je; j += 8) {
    int s0 = csr[j + grp];
    int s1 = csr[j + 4 + grp];
    float o0 = invO[s0], o1 = invO[s1];
    uint4e v0 = __builtin_nontemporal_load(&xwq[(size_t)s0 * 16 + sl]);
    uint4e v1 = __builtin_nontemporal_load(&xwq[(size_t)s1 * 16 + sl]);
    ACC8(v0, o0);
    ACC8(v1, o1);
  }
  for (; j < je; j += 4) {
    int e = j + grp;
    if (e < je) {
      int s = csr[e];
      float o = invO[s];
      uint4e v = __builtin_nontemporal_load(&xwq[(size_t)s * 16 + sl]);
      ACC8(v, o);
    }
  }
#undef ACC8

  a0 += __shfl_xor(a0, 16); a0 += __shfl_xor(a0, 32);
  a1 += __shfl_xor(a1, 16); a1 += __shfl_xor(a1, 32);
  a2 += __shfl_xor(a2, 16); a2 += __shfl_xor(a2, 32);
  a3 += __shfl_xor(a3, 16); a3 += __shfl_xor(a3, 32);
  a4 += __shfl_xor(a4, 16); a4 += __shfl_xor(a4, 32);
  a5 += __shfl_xor(a5, 16); a5 += __shfl_xor(a5, 32);
  a6 += __shfl_xor(a6, 16); a6 += __shfl_xor(a6, 32);
  a7 += __shfl_xor(a7, 16); a7 += __shfl_xor(a7, 32);

  float inI = invI[i];
  int f = sl * 8;
  float4 bl = *(const float4*)&b1[f];
  float4 bh = *(const float4*)&b1[f + 4];
  float4 wl = *(const float4*)&W2[f];
  float4 wh = *(const float4*)&W2[f + 4];
  float p = fmaxf(fmaf(a0, inI, bl.x), 0.f) * wl.x
          + fmaxf(fmaf(a1, inI, bl.y), 0.f) * wl.y
          + fmaxf(fmaf(a2, inI, bl.z), 0.f) * wl.z
          + fmaxf(fmaf(a3, inI, bl.w), 0.f) * wl.w
          + fmaxf(fmaf(a4, inI, bh.x), 0.f) * wh.x
          + fmaxf(fmaf(a5, inI, bh.y), 0.f) * wh.y
          + fmaxf(fmaf(a6, inI, bh.z), 0.f) * wh.z
          + fmaxf(fmaf(a7, inI, bh.w), 0.f) * wh.w;
#pragma unroll
  for (int off = 8; off; off >>= 1) p += __shfl_xor(p, off);
  if (lane == 0) h2[i] = p * invO[i];
}

// ---------------- layer-2 gather + epilogue (4 lanes per node) ----------------
__global__ __launch_bounds__(256) void k_gather2(const float* __restrict__ h2,
                                                 const int* __restrict__ rowoff,
                                                 const int* __restrict__ csr,
                                                 const float* __restrict__ invI,
                                                 const float* __restrict__ b2,
                                                 float* __restrict__ out, int N) {
  int i = blockIdx.x * 64 + (threadIdx.x >> 2);
  int q = threadIdx.x & 3;
  if (i >= N) return;
  int jb = rowoff[i];
  int je = rowoff[i + 1];
  float s = 0.f;
  for (int j = jb + q; j < je; j += 4) s += h2[csr[j]];
  s += __shfl_xor(s, 1);
  s += __shfl_xor(s, 2);
  if (q == 0) out[i] = s * invI[i] + b2[0];
}

extern "C" void kernel_launch(void* const* d_in, const int* in_sizes, int n_in,
                              void* d_out, int out_size, void* d_ws, size_t ws_size,
                              hipStream_t stream) {
  const float* x   = (const float*)d_in[0];
  const int*   src = (const int*)d_in[1];
  const int*   dst = (const int*)d_in[2];
  const float* W1  = (const float*)d_in[3];
  const float* b1  = (const float*)d_in[4];
  const float* W2  = (const float*)d_in[5];
  const float* b2  = (const float*)d_in[6];
  int N = in_sizes[0] / NF;
  int E = in_sizes[1];
  int NB = (N + 255) >> 8;             // <= 512

  int* bucketCnt  = (int*)d_ws;                    // 512
  int* bucketCntS = bucketCnt + 512;               // 512
  unsigned short* WbT = (unsigned short*)(bucketCntS + 512);  // 128*128 bf16 (32 KB)
  int* rowoff     = (int*)(WbT + NF * NF);         // N+1 (pad to N+8)
  int* csr        = rowoff + (size_t)N + 8;        // E
  int2* region    = (int2*)(csr + (size_t)E);      // NB*CAP int2
  int* regionS    = (int*)(region + (size_t)NB * CAP);  // NB*CAP int
  float* invO     = (float*)(regionS + (size_t)NB * CAP);
  float* invI     = invO + N;
  float* h2       = invI + N;
  unsigned short* xw = (unsigned short*)(h2 + N);  // N*128 bf16
  float* out      = (float*)d_out;

  int B1 = (E + EPB - 1) / EPB;        // binA role blocks
  int B2 = (E + EPB2 - 1) / EPB2;      // binA2 role blocks
  int BW = 16;                         // W-convert role blocks
  int G  = (N + 63) / 64;              // MFMA gemm role blocks

  k_init<<<1, 256, 0, stream>>>(bucketCnt, bucketCntS, rowoff, N, E);
  k_frontA<<<B1 + B2 + BW, 256, 0, stream>>>(src, dst, W1, bucketCnt, bucketCntS,
                                             region, regionS, WbT, E, B1, B2);
  k_mid<<<2 * NB + G, 256, 0, stream>>>(x, WbT, region, bucketCnt, regionS, bucketCntS,
                                        csr, rowoff, invI, invO, xw, N, NB);
  k_gather_proj<<<(N + 3) / 4, 256, 0, stream>>>(xw, rowoff, csr, invI, invO, b1, W2, h2, N);
  k_gather2<<<(N + 63) / 64, 256, 0, stream>>>(h2, rowoff, csr, invI, b2, out, N);
}

// Round 18
// 169.801 us; speedup vs baseline: 1.1974x; 1.1974x over previous
//
#include <hip/hip_runtime.h>
#include <hip/hip_bf16.h>

#define NF 128
#define EPB 4096      // edges per binA role block (int2 staging, 32 KB)
#define EPB2 8192     // edges per binA2 role block (int staging, 32 KB)
#define CAP 6144      // per-bucket region capacity (mean 4096, +32 sigma)

typedef __attribute__((ext_vector_type(8))) short short8;   // 8 bf16 (4 VGPRs)
typedef __attribute__((ext_vector_type(4))) float f32x4;    // MFMA acc
typedef __attribute__((ext_vector_type(4))) unsigned int uint4e;

// ---------------- init (1 block) ----------------
__global__ void k_init(int* __restrict__ bucketCnt, int* __restrict__ bucketCntS,
                       int* __restrict__ rowoff, int N, int E) {
  int i = threadIdx.x;
  for (int k = i; k < 512; k += 256) { bucketCnt[k] = 0; bucketCntS[k] = 0; }
  if (i == 0) rowoff[N] = E;
}

// ---------------- frontA: binA | binA2 | W1->bf16^T convert ----------------
__global__ __launch_bounds__(256) void k_frontA(const int* __restrict__ src,
                                                const int* __restrict__ dst,
                                                const float* __restrict__ W1,
                                                int* __restrict__ bucketCnt,
                                                int* __restrict__ bucketCntS,
                                                int2* __restrict__ region,
                                                int* __restrict__ regionS,
                                                unsigned short* __restrict__ WbT,
                                                int E, int B1, int B2) {
  __shared__ __align__(16) char smem_raw[42240];  // 9216 ctl + 32768 staging
  int* cnt   = (int*)smem_raw;
  int* scanv = cnt + 512;
  int* cur   = scanv + 512;
  int* gb    = cur + 512;
  int* s1    = gb + 512;
  void* stv  = (void*)(smem_raw + 9216 + 256);  // 16B-aligned staging
  int tid = threadIdx.x;
  int b = blockIdx.x;

  if (b >= B1 + B2) {
    // ---- W-convert role (16 blocks): WbT[n][k] = bf16(W1[k][n]) ----
    int u = (b - B1 - B2) * 256 + tid;   // 0..4095 ushort4 units
    int n  = u >> 5;
    int k4 = (u & 31) << 2;
    ushort4 o;
    __hip_bfloat16 h0 = __float2bfloat16(W1[(k4 + 0) * NF + n]);
    __hip_bfloat16 h1 = __float2bfloat16(W1[(k4 + 1) * NF + n]);
    __hip_bfloat16 h2 = __float2bfloat16(W1[(k4 + 2) * NF + n]);
    __hip_bfloat16 h3 = __float2bfloat16(W1[(k4 + 3) * NF + n]);
    o.x = *(unsigned short*)&h0;
    o.y = *(unsigned short*)&h1;
    o.z = *(unsigned short*)&h2;
    o.w = *(unsigned short*)&h3;
    *(ushort4*)&WbT[n * NF + k4] = o;
    return;
  }

  if (b < B1) {
    // ---- binA role: bin (dst,src) pairs into 256-node buckets ----
    int2* st = (int2*)stv;
    int b0 = b * EPB;
    int n = E - b0; if (n > EPB) n = EPB;

    for (int k = tid; k < 512; k += 256) cnt[k] = 0;
    __syncthreads();
    for (int k = tid; k < n; k += 256) atomicAdd(&cnt[dst[b0 + k] >> 8], 1);
    __syncthreads();

    int c0 = cnt[2 * tid], c1 = cnt[2 * tid + 1];
    s1[tid] = c0 + c1;
    __syncthreads();
    for (int off = 1; off < 256; off <<= 1) {
      int v = (tid >= off) ? s1[tid - off] : 0;
      __syncthreads();
      s1[tid] += v;
      __syncthreads();
    }
    int excl = tid ? s1[tid - 1] : 0;
    scanv[2 * tid] = excl;
    scanv[2 * tid + 1] = excl + c0;
    cur[2 * tid] = excl;
    cur[2 * tid + 1] = excl + c0;
    gb[2 * tid]     = c0 ? atomicAdd(&bucketCnt[2 * tid], c0) : 0;
    gb[2 * tid + 1] = c1 ? atomicAdd(&bucketCnt[2 * tid + 1], c1) : 0;
    __syncthreads();

    for (int k = tid; k < n; k += 256) {
      int d = dst[b0 + k], s = src[b0 + k];
      int p = atomicAdd(&cur[d >> 8], 1);
      st[p] = make_int2(d, s);
    }
    __syncthreads();
    for (int k = tid; k < n; k += 256) {
      int2 e = st[k];
      int bk = e.x >> 8;
      int gp = gb[bk] + (k - scanv[bk]);
      if (gp < CAP) region[(size_t)bk * CAP + gp] = e;
    }
    return;
  }

  // ---- binA2 role: bin bare src values (out-degree) ----
  int* st = (int*)stv;
  int b0 = (b - B1) * EPB2;
  int n = E - b0; if (n > EPB2) n = EPB2;

  for (int k = tid; k < 512; k += 256) cnt[k] = 0;
  __syncthreads();
  for (int k = tid; k < n; k += 256) atomicAdd(&cnt[src[b0 + k] >> 8], 1);
  __syncthreads();

  int c0 = cnt[2 * tid], c1 = cnt[2 * tid + 1];
  s1[tid] = c0 + c1;
  __syncthreads();
  for (int off = 1; off < 256; off <<= 1) {
    int v = (tid >= off) ? s1[tid - off] : 0;
    __syncthreads();
    s1[tid] += v;
    __syncthreads();
  }
  int excl = tid ? s1[tid - 1] : 0;
  scanv[2 * tid] = excl;
  scanv[2 * tid + 1] = excl + c0;
  cur[2 * tid] = excl;
  cur[2 * tid + 1] = excl + c0;
  gb[2 * tid]     = c0 ? atomicAdd(&bucketCntS[2 * tid], c0) : 0;
  gb[2 * tid + 1] = c1 ? atomicAdd(&bucketCntS[2 * tid + 1], c1) : 0;
  __syncthreads();

  for (int k = tid; k < n; k += 256) {
    int s = src[b0 + k];
    int p = atomicAdd(&cur[s >> 8], 1);
    st[p] = s;
  }
  __syncthreads();
  for (int k = tid; k < n; k += 256) {
    int s = st[k];
    int bk = s >> 8;
    int gp = gb[bk] + (k - scanv[bk]);
    if (gp < CAP) regionS[(size_t)bk * CAP + gp] = s;
  }
}

// ---------------- mid: binB | binB2 | MFMA gemm1 (bf16 W pre-staged) ----------------
__global__ __launch_bounds__(256) void k_mid(const float* __restrict__ x,
                                             const unsigned short* __restrict__ WbT,
                                             const int2* __restrict__ region,
                                             const int* __restrict__ bucketCnt,
                                             const int* __restrict__ regionS,
                                             const int* __restrict__ bucketCntS,
                                             int* __restrict__ csr,
                                             int* __restrict__ rowoff,
                                             float* __restrict__ invI,
                                             float* __restrict__ invO,
                                             unsigned short* __restrict__ xw,
                                             int N, int NB) {
  __shared__ __align__(16) char smem_raw[52224];
  int tid = threadIdx.x;
  int blk = blockIdx.x;

  if (blk < NB) {
    // ---- binB role: counting sort -> csr + rowoff + invI ----
    int* s1   = (int*)smem_raw;
    int* hist = s1 + 256;
    int* incl = hist + 256;
    int* cur  = incl + 256;
    int b = blk;
    int c0 = (2 * tid < NB) ? bucketCnt[2 * tid] : 0;
    int c1 = (2 * tid + 1 < NB) ? bucketCnt[2 * tid + 1] : 0;
    s1[tid] = c0 + c1;
    __syncthreads();
    for (int off = 1; off < 256; off <<= 1) {
      int v = (tid >= off) ? s1[tid - off] : 0;
      __syncthreads();
      s1[tid] += v;
      __syncthreads();
    }
    int t = b >> 1;
    int csrBase = t ? s1[t - 1] : 0;
    if (b & 1) csrBase += bucketCnt[b & ~1];

    int base = b << 8;
    int nN = N - base; if (nN > 256) nN = 256;
    int cntb = bucketCnt[b]; if (cntb > CAP) cntb = CAP;
    const int2* reg = region + (size_t)b * CAP;

    hist[tid] = 0;
    __syncthreads();
    for (int k = tid; k < cntb; k += 256) atomicAdd(&hist[reg[k].x - base], 1);
    __syncthreads();
    int h = hist[tid];
    incl[tid] = h;
    __syncthreads();
    for (int off = 1; off < 256; off <<= 1) {
      int v = (tid >= off) ? incl[tid - off] : 0;
      __syncthreads();
      incl[tid] += v;
      __syncthreads();
    }
    int startt = incl[tid] - h;  // exclusive
    if (tid < nN) {
      rowoff[base + tid] = csrBase + startt;
      invI[base + tid] = rsqrtf(fmaxf((float)h, 1.0f));
    }
    cur[tid] = startt;
    __syncthreads();
    for (int k = tid; k < cntb; k += 256) {
      int2 e = reg[k];
      int p = atomicAdd(&cur[e.x - base], 1);
      csr[csrBase + p] = e.y;
    }
    return;
  }

  if (blk < 2 * NB) {
    // ---- binB2 role: src histogram -> invO ----
    int* hist = (int*)smem_raw;
    int b = blk - NB;
    int base = b << 8;
    int cntb = bucketCntS[b]; if (cntb > CAP) cntb = CAP;
    const int* reg = regionS + (size_t)b * CAP;
    hist[tid] = 0;
    __syncthreads();
    for (int k = tid; k < cntb; k += 256) atomicAdd(&hist[reg[k] - base], 1);
    __syncthreads();
    if (base + tid < N) invO[base + tid] = rsqrtf(fmaxf((float)hist[tid], 1.0f));
    return;
  }

  // ---- gemm role (MFMA): xw[64 rows] = bf16( x @ W1 ) ----
  unsigned short* Wb = (unsigned short*)smem_raw;   // [128][136]
  unsigned short* Xb = Wb + 128 * 136;              // [64][136]
  int idx = blk - 2 * NB;
  int rowbase = idx * 64;

  // stage x tile first (cold long-latency stream): Xb[r][k] = bf16(x[rowbase+r][k])
  for (int t = tid; t < 64 * 32; t += 256) {
    int r = t >> 5, k4 = (t & 31) << 2;
    int row = rowbase + r; if (row >= N) row = N - 1;
    float4 v = *(const float4*)&x[(size_t)row * NF + k4];
    __hip_bfloat16 h0 = __float2bfloat16(v.x);
    __hip_bfloat16 h1 = __float2bfloat16(v.y);
    __hip_bfloat16 h2 = __float2bfloat16(v.z);
    __hip_bfloat16 h3 = __float2bfloat16(v.w);
    ushort4 u;
    u.x = *(unsigned short*)&h0;
    u.y = *(unsigned short*)&h1;
    u.z = *(unsigned short*)&h2;
    u.w = *(unsigned short*)&h3;
    *(ushort4*)&Xb[r * 136 + k4] = u;
  }
  // stage pre-converted W^T: straight 16B copies (L2-hot 32 KB)
  for (int t = tid; t < 128 * 16; t += 256) {
    int n = t >> 4, k8 = (t & 15) << 3;
    short8 v = *(const short8*)&WbT[n * NF + k8];
    *(short8*)&Wb[n * 136 + k8] = v;
  }
  __syncthreads();

  int w    = tid >> 6;   // wave 0..3 -> rows w*16..w*16+15
  int lane = tid & 63;
  int r16  = lane & 15;
  int kg   = lane >> 4;  // 0..3

  short8 afrag[4];
#pragma unroll
  for (int kk = 0; kk < 4; ++kk) {
    afrag[kk] = *(const short8*)&Xb[(w * 16 + r16) * 136 + kg * 8 + kk * 32];
  }

#pragma unroll
  for (int ct = 0; ct < 8; ++ct) {
    f32x4 acc = {0.f, 0.f, 0.f, 0.f};
#pragma unroll
    for (int kk = 0; kk < 4; ++kk) {
      short8 bfrag = *(const short8*)&Wb[(ct * 16 + r16) * 136 + kg * 8 + kk * 32];
      acc = __builtin_amdgcn_mfma_f32_16x16x32_bf16(afrag[kk], bfrag, acc, 0, 0, 0);
    }
#pragma unroll
    for (int reg = 0; reg < 4; ++reg) {
      int row = rowbase + w * 16 + kg * 4 + reg;
      if (row < N) {
        __hip_bfloat16 hb = __float2bfloat16(acc[reg]);
        xw[(size_t)row * NF + ct * 16 + r16] = *(unsigned short*)&hb;
      }
    }
  }
}

// ---------------- fused gather + layer-2 projection (plain uint4 loads) ----------------
__global__ __launch_bounds__(256) void k_gather_proj(const unsigned short* __restrict__ xw,
                                                     const int* __restrict__ rowoff,
                                                     const int* __restrict__ csr,
                                                     const float* __restrict__ invI,
                                                     const float* __restrict__ invO,
                                                     const float* __restrict__ b1,
                                                     const float* __restrict__ W2,
                                                     float* __restrict__ h2, int N) {
  int i    = blockIdx.x * 4 + (threadIdx.x >> 6);
  int lane = threadIdx.x & 63;
  int grp  = lane >> 4;   // 0..3
  int sl   = lane & 15;
  if (i >= N) return;
  int jb = rowoff[i];
  int je = rowoff[i + 1];
  const uint4e* xwq = (const uint4e*)xw;  // 16 uint4e per row
  float a0 = 0.f, a1 = 0.f, a2 = 0.f, a3 = 0.f;
  float a4 = 0.f, a5 = 0.f, a6 = 0.f, a7 = 0.f;

#define ACC8(v, o)                                                         \
  do {                                                                     \
    a0 = fmaf(__uint_as_float(((v).x & 0xffffu) << 16), (o), a0);          \
    a1 = fmaf(__uint_as_float((v).x & 0xffff0000u), (o), a1);              \
    a2 = fmaf(__uint_as_float(((v).y & 0xffffu) << 16), (o), a2);          \
    a3 = fmaf(__uint_as_float((v).y & 0xffff0000u), (o), a3);              \
    a4 = fmaf(__uint_as_float(((v).z & 0xffffu) << 16), (o), a4);          \
    a5 = fmaf(__uint_as_float((v).z & 0xffff0000u), (o), a5);              \
    a6 = fmaf(__uint_as_float(((v).w & 0xffffu) << 16), (o), a6);          \
    a7 = fmaf(__uint_as_float((v).w & 0xffff0000u), (o), a7);              \
  } while (0)

  int j = jb;
  for (; j + 8 <= je; j += 8) {
    int s0 = csr[j + grp];
    int s1 = csr[j + 4 + grp];
    float o0 = invO[s0], o1 = invO[s1];
    uint4e v0 = xwq[(size_t)s0 * 16 + sl];
    uint4e v1 = xwq[(size_t)s1 * 16 + sl];
    ACC8(v0, o0);
    ACC8(v1, o1);
  }
  for (; j < je; j += 4) {
    int e = j + grp;
    if (e < je) {
      int s = csr[e];
      float o = invO[s];
      uint4e v = xwq[(size_t)s * 16 + sl];
      ACC8(v, o);
    }
  }
#undef ACC8

  a0 += __shfl_xor(a0, 16); a0 += __shfl_xor(a0, 32);
  a1 += __shfl_xor(a1, 16); a1 += __shfl_xor(a1, 32);
  a2 += __shfl_xor(a2, 16); a2 += __shfl_xor(a2, 32);
  a3 += __shfl_xor(a3, 16); a3 += __shfl_xor(a3, 32);
  a4 += __shfl_xor(a4, 16); a4 += __shfl_xor(a4, 32);
  a5 += __shfl_xor(a5, 16); a5 += __shfl_xor(a5, 32);
  a6 += __shfl_xor(a6, 16); a6 += __shfl_xor(a6, 32);
  a7 += __shfl_xor(a7, 16); a7 += __shfl_xor(a7, 32);

  float inI = invI[i];
  int f = sl * 8;
  float4 bl = *(const float4*)&b1[f];
  float4 bh = *(const float4*)&b1[f + 4];
  float4 wl = *(const float4*)&W2[f];
  float4 wh = *(const float4*)&W2[f + 4];
  float p = fmaxf(fmaf(a0, inI, bl.x), 0.f) * wl.x
          + fmaxf(fmaf(a1, inI, bl.y), 0.f) * wl.y
          + fmaxf(fmaf(a2, inI, bl.z), 0.f) * wl.z
          + fmaxf(fmaf(a3, inI, bl.w), 0.f) * wl.w
          + fmaxf(fmaf(a4, inI, bh.x), 0.f) * wh.x
          + fmaxf(fmaf(a5, inI, bh.y), 0.f) * wh.y
          + fmaxf(fmaf(a6, inI, bh.z), 0.f) * wh.z
          + fmaxf(fmaf(a7, inI, bh.w), 0.f) * wh.w;
#pragma unroll
  for (int off = 8; off; off >>= 1) p += __shfl_xor(p, off);
  if (lane == 0) h2[i] = p * invO[i];
}

// ---------------- layer-2 gather + epilogue (4 lanes per node) ----------------
__global__ __launch_bounds__(256) void k_gather2(const float* __restrict__ h2,
                                                 const int* __restrict__ rowoff,
                                                 const int* __restrict__ csr,
                                                 const float* __restrict__ invI,
                                                 const float* __restrict__ b2,
                                                 float* __restrict__ out, int N) {
  int i = blockIdx.x * 64 + (threadIdx.x >> 2);
  int q = threadIdx.x & 3;
  if (i >= N) return;
  int jb = rowoff[i];
  int je = rowoff[i + 1];
  float s = 0.f;
  for (int j = jb + q; j < je; j += 4) s += h2[csr[j]];
  s += __shfl_xor(s, 1);
  s += __shfl_xor(s, 2);
  if (q == 0) out[i] = s * invI[i] + b2[0];
}

extern "C" void kernel_launch(void* const* d_in, const int* in_sizes, int n_in,
                              void* d_out, int out_size, void* d_ws, size_t ws_size,
                              hipStream_t stream) {
  const float* x   = (const float*)d_in[0];
  const int*   src = (const int*)d_in[1];
  const int*   dst = (const int*)d_in[2];
  const float* W1  = (const float*)d_in[3];
  const float* b1  = (const float*)d_in[4];
  const float* W2  = (const float*)d_in[5];
  const float* b2  = (const float*)d_in[6];
  int N = in_sizes[0] / NF;
  int E = in_sizes[1];
  int NB = (N + 255) >> 8;             // <= 512

  int* bucketCnt  = (int*)d_ws;                    // 512
  int* bucketCntS = bucketCnt + 512;               // 512
  unsigned short* WbT = (unsigned short*)(bucketCntS + 512);  // 128*128 bf16 (32 KB)
  int* rowoff     = (int*)(WbT + NF * NF);         // N+1 (pad to N+8)
  int* csr        = rowoff + (size_t)N + 8;        // E
  int2* region    = (int2*)(csr + (size_t)E);      // NB*CAP int2
  int* regionS    = (int*)(region + (size_t)NB * CAP);  // NB*CAP int
  float* invO     = (float*)(regionS + (size_t)NB * CAP);
  float* invI     = invO + N;
  float* h2       = invI + N;
  unsigned short* xw = (unsigned short*)(h2 + N);  // N*128 bf16
  float* out      = (float*)d_out;

  int B1 = (E + EPB - 1) / EPB;        // binA role blocks
  int B2 = (E + EPB2 - 1) / EPB2;      // binA2 role blocks
  int BW = 16;                         // W-convert role blocks
  int G  = (N + 63) / 64;              // MFMA gemm role blocks

  k_init<<<1, 256, 0, stream>>>(bucketCnt, bucketCntS, rowoff, N, E);
  k_frontA<<<B1 + B2 + BW, 256, 0, stream>>>(src, dst, W1, bucketCnt, bucketCntS,
                                             region, regionS, WbT, E, B1, B2);
  k_mid<<<2 * NB + G, 256, 0, stream>>>(x, WbT, region, bucketCnt, regionS, bucketCntS,
                                        csr, rowoff, invI, invO, xw, N, NB);
  k_gather_proj<<<(N + 3) / 4, 256, 0, stream>>>(xw, rowoff, csr, invI, invO, b1, W2, h2, N);
  k_gather2<<<(N + 63) / 64, 256, 0, stream>>>(h2, rowoff, csr, invI, b2, out, N);
}

// Round 19
// 163.128 us; speedup vs baseline: 1.2464x; 1.0409x over previous
//
#include <hip/hip_runtime.h>
#include <hip/hip_bf16.h>

#define NF 128
#define EPB 4096      // edges per binA role block (int2 staging, 32 KB)
#define EPB2 8192     // edges per binA2 role block (int staging, 32 KB)
#define CAP 6144      // per-bucket region capacity (mean 4096, +32 sigma)

typedef __attribute__((ext_vector_type(8))) short short8;   // 8 bf16 (4 VGPRs)
typedef __attribute__((ext_vector_type(4))) float f32x4;    // MFMA acc
typedef __attribute__((ext_vector_type(4))) unsigned int uint4e;

// ---------------- init (16 blocks): zero counters + W1 -> bf16^T ----------------
__global__ __launch_bounds__(256) void k_init(const float* __restrict__ W1,
                                              int* __restrict__ bucketCnt,
                                              int* __restrict__ bucketCntS,
                                              int* __restrict__ rowoff,
                                              unsigned short* __restrict__ WbT,
                                              int N, int E) {
  int tid = threadIdx.x;
  int b = blockIdx.x;
  if (b == 0) {
    for (int k = tid; k < 512; k += 256) { bucketCnt[k] = 0; bucketCntS[k] = 0; }
    if (tid == 0) rowoff[N] = E;
  }
  // WbT[n][k] = bf16(W1[k][n]); 16 blocks x 256 threads = 4096 ushort4 units
  int u = b * 256 + tid;
  int n  = u >> 5;
  int k4 = (u & 31) << 2;
  ushort4 o;
  __hip_bfloat16 h0 = __float2bfloat16(W1[(k4 + 0) * NF + n]);
  __hip_bfloat16 h1 = __float2bfloat16(W1[(k4 + 1) * NF + n]);
  __hip_bfloat16 h2 = __float2bfloat16(W1[(k4 + 2) * NF + n]);
  __hip_bfloat16 h3 = __float2bfloat16(W1[(k4 + 3) * NF + n]);
  o.x = *(unsigned short*)&h0;
  o.y = *(unsigned short*)&h1;
  o.z = *(unsigned short*)&h2;
  o.w = *(unsigned short*)&h3;
  *(ushort4*)&WbT[n * NF + k4] = o;
}

// ---------------- front: binA | binA2 | MFMA gemm1 ----------------
__global__ __launch_bounds__(256) void k_front(const float* __restrict__ x,
                                               const int* __restrict__ src,
                                               const int* __restrict__ dst,
                                               const unsigned short* __restrict__ WbT,
                                               int* __restrict__ bucketCnt,
                                               int* __restrict__ bucketCntS,
                                               int2* __restrict__ region,
                                               int* __restrict__ regionS,
                                               unsigned short* __restrict__ xw,
                                               int N, int E, int B1, int B2) {
  __shared__ __align__(16) char smem_raw[52224];
  int tid = threadIdx.x;
  int b = blockIdx.x;

  if (b < B1) {
    // ---- binA role: bin (dst,src) pairs into 256-node buckets ----
    int* cnt   = (int*)smem_raw;
    int* scanv = cnt + 512;
    int* cur   = scanv + 512;
    int* gb    = cur + 512;
    int* s1    = gb + 512;
    int2* st   = (int2*)(smem_raw + 9216 + 256);
    int b0 = b * EPB;
    int n = E - b0; if (n > EPB) n = EPB;

    for (int k = tid; k < 512; k += 256) cnt[k] = 0;
    __syncthreads();
    for (int k = tid; k < n; k += 256) atomicAdd(&cnt[dst[b0 + k] >> 8], 1);
    __syncthreads();

    int c0 = cnt[2 * tid], c1 = cnt[2 * tid + 1];
    s1[tid] = c0 + c1;
    __syncthreads();
    for (int off = 1; off < 256; off <<= 1) {
      int v = (tid >= off) ? s1[tid - off] : 0;
      __syncthreads();
      s1[tid] += v;
      __syncthreads();
    }
    int excl = tid ? s1[tid - 1] : 0;
    scanv[2 * tid] = excl;
    scanv[2 * tid + 1] = excl + c0;
    cur[2 * tid] = excl;
    cur[2 * tid + 1] = excl + c0;
    gb[2 * tid]     = c0 ? atomicAdd(&bucketCnt[2 * tid], c0) : 0;
    gb[2 * tid + 1] = c1 ? atomicAdd(&bucketCnt[2 * tid + 1], c1) : 0;
    __syncthreads();

    for (int k = tid; k < n; k += 256) {
      int d = dst[b0 + k], s = src[b0 + k];
      int p = atomicAdd(&cur[d >> 8], 1);
      st[p] = make_int2(d, s);
    }
    __syncthreads();
    for (int k = tid; k < n; k += 256) {
      int2 e = st[k];
      int bk = e.x >> 8;
      int gp = gb[bk] + (k - scanv[bk]);
      if (gp < CAP) region[(size_t)bk * CAP + gp] = e;
    }
    return;
  }

  if (b < B1 + B2) {
    // ---- binA2 role: bin bare src values (out-degree) ----
    int* cnt   = (int*)smem_raw;
    int* scanv = cnt + 512;
    int* cur   = scanv + 512;
    int* gb    = cur + 512;
    int* s1    = gb + 512;
    int* st    = (int*)(smem_raw + 9216 + 256);
    int b0 = (b - B1) * EPB2;
    int n = E - b0; if (n > EPB2) n = EPB2;

    for (int k = tid; k < 512; k += 256) cnt[k] = 0;
    __syncthreads();
    for (int k = tid; k < n; k += 256) atomicAdd(&cnt[src[b0 + k] >> 8], 1);
    __syncthreads();

    int c0 = cnt[2 * tid], c1 = cnt[2 * tid + 1];
    s1[tid] = c0 + c1;
    __syncthreads();
    for (int off = 1; off < 256; off <<= 1) {
      int v = (tid >= off) ? s1[tid - off] : 0;
      __syncthreads();
      s1[tid] += v;
      __syncthreads();
    }
    int excl = tid ? s1[tid - 1] : 0;
    scanv[2 * tid] = excl;
    scanv[2 * tid + 1] = excl + c0;
    cur[2 * tid] = excl;
    cur[2 * tid + 1] = excl + c0;
    gb[2 * tid]     = c0 ? atomicAdd(&bucketCntS[2 * tid], c0) : 0;
    gb[2 * tid + 1] = c1 ? atomicAdd(&bucketCntS[2 * tid + 1], c1) : 0;
    __syncthreads();

    for (int k = tid; k < n; k += 256) {
      int s = src[b0 + k];
      int p = atomicAdd(&cur[s >> 8], 1);
      st[p] = s;
    }
    __syncthreads();
    for (int k = tid; k < n; k += 256) {
      int s = st[k];
      int bk = s >> 8;
      int gp = gb[bk] + (k - scanv[bk]);
      if (gp < CAP) regionS[(size_t)bk * CAP + gp] = s;
    }
    return;
  }

  // ---- gemm role (MFMA): xw[64 rows] = bf16( x @ W1 ) ----
  unsigned short* Wb = (unsigned short*)smem_raw;   // [128][136]
  unsigned short* Xb = Wb + 128 * 136;              // [64][136]
  int idx = b - B1 - B2;
  int rowbase = idx * 64;

  // stage x tile first (cold long-latency stream)
  for (int t = tid; t < 64 * 32; t += 256) {
    int r = t >> 5, k4 = (t & 31) << 2;
    int row = rowbase + r; if (row >= N) row = N - 1;
    float4 v = *(const float4*)&x[(size_t)row * NF + k4];
    __hip_bfloat16 h0 = __float2bfloat16(v.x);
    __hip_bfloat16 h1 = __float2bfloat16(v.y);
    __hip_bfloat16 h2 = __float2bfloat16(v.z);
    __hip_bfloat16 h3 = __float2bfloat16(v.w);
    ushort4 u;
    u.x = *(unsigned short*)&h0;
    u.y = *(unsigned short*)&h1;
    u.z = *(unsigned short*)&h2;
    u.w = *(unsigned short*)&h3;
    *(ushort4*)&Xb[r * 136 + k4] = u;
  }
  // stage pre-converted W^T: straight 16B copies (L2-hot 32 KB)
  for (int t = tid; t < 128 * 16; t += 256) {
    int n = t >> 4, k8 = (t & 15) << 3;
    short8 v = *(const short8*)&WbT[n * NF + k8];
    *(short8*)&Wb[n * 136 + k8] = v;
  }
  __syncthreads();

  int w    = tid >> 6;   // wave 0..3 -> rows w*16..w*16+15
  int lane = tid & 63;
  int r16  = lane & 15;
  int kg   = lane >> 4;  // 0..3

  short8 afrag[4];
#pragma unroll
  for (int kk = 0; kk < 4; ++kk) {
    afrag[kk] = *(const short8*)&Xb[(w * 16 + r16) * 136 + kg * 8 + kk * 32];
  }

#pragma unroll
  for (int ct = 0; ct < 8; ++ct) {
    f32x4 acc = {0.f, 0.f, 0.f, 0.f};
#pragma unroll
    for (int kk = 0; kk < 4; ++kk) {
      short8 bfrag = *(const short8*)&Wb[(ct * 16 + r16) * 136 + kg * 8 + kk * 32];
      acc = __builtin_amdgcn_mfma_f32_16x16x32_bf16(afrag[kk], bfrag, acc, 0, 0, 0);
    }
#pragma unroll
    for (int reg = 0; reg < 4; ++reg) {
      int row = rowbase + w * 16 + kg * 4 + reg;
      if (row < N) {
        __hip_bfloat16 hb = __float2bfloat16(acc[reg]);
        xw[(size_t)row * NF + ct * 16 + r16] = *(unsigned short*)&hb;
      }
    }
  }
}

// ---------------- mid2: binB | binB2 ----------------
__global__ __launch_bounds__(256) void k_mid2(const int2* __restrict__ region,
                                              const int* __restrict__ bucketCnt,
                                              const int* __restrict__ regionS,
                                              const int* __restrict__ bucketCntS,
                                              int* __restrict__ csr,
                                              int* __restrict__ rowoff,
                                              float* __restrict__ invI,
                                              float* __restrict__ invO,
                                              int N, int NB) {
  __shared__ int s1[256], hist[256], incl[256], cur[256];
  int tid = threadIdx.x;
  int blk = blockIdx.x;

  if (blk < NB) {
    // ---- binB role: counting sort -> csr + rowoff + invI ----
    int b = blk;
    int c0 = (2 * tid < NB) ? bucketCnt[2 * tid] : 0;
    int c1 = (2 * tid + 1 < NB) ? bucketCnt[2 * tid + 1] : 0;
    s1[tid] = c0 + c1;
    __syncthreads();
    for (int off = 1; off < 256; off <<= 1) {
      int v = (tid >= off) ? s1[tid - off] : 0;
      __syncthreads();
      s1[tid] += v;
      __syncthreads();
    }
    int t = b >> 1;
    int csrBase = t ? s1[t - 1] : 0;
    if (b & 1) csrBase += bucketCnt[b & ~1];

    int base = b << 8;
    int nN = N - base; if (nN > 256) nN = 256;
    int cntb = bucketCnt[b]; if (cntb > CAP) cntb = CAP;
    const int2* reg = region + (size_t)b * CAP;

    hist[tid] = 0;
    __syncthreads();
    for (int k = tid; k < cntb; k += 256) atomicAdd(&hist[reg[k].x - base], 1);
    __syncthreads();
    int h = hist[tid];
    incl[tid] = h;
    __syncthreads();
    for (int off = 1; off < 256; off <<= 1) {
      int v = (tid >= off) ? incl[tid - off] : 0;
      __syncthreads();
      incl[tid] += v;
      __syncthreads();
    }
    int startt = incl[tid] - h;  // exclusive
    if (tid < nN) {
      rowoff[base + tid] = csrBase + startt;
      invI[base + tid] = rsqrtf(fmaxf((float)h, 1.0f));
    }
    cur[tid] = startt;
    __syncthreads();
    for (int k = tid; k < cntb; k += 256) {
      int2 e = reg[k];
      int p = atomicAdd(&cur[e.x - base], 1);
      csr[csrBase + p] = e.y;
    }
    return;
  }

  // ---- binB2 role: src histogram -> invO ----
  int b = blk - NB;
  int base = b << 8;
  int cntb = bucketCntS[b]; if (cntb > CAP) cntb = CAP;
  const int* reg = regionS + (size_t)b * CAP;
  hist[tid] = 0;
  __syncthreads();
  for (int k = tid; k < cntb; k += 256) atomicAdd(&hist[reg[k] - base], 1);
  __syncthreads();
  if (base + tid < N) invO[base + tid] = rsqrtf(fmaxf((float)hist[tid], 1.0f));
}

// ---------------- fused gather + layer-2 projection (plain uint4 loads) ----------------
__global__ __launch_bounds__(256) void k_gather_proj(const unsigned short* __restrict__ xw,
                                                     const int* __restrict__ rowoff,
                                                     const int* __restrict__ csr,
                                                     const float* __restrict__ invI,
                                                     const float* __restrict__ invO,
                                                     const float* __restrict__ b1,
                                                     const float* __restrict__ W2,
                                                     float* __restrict__ h2, int N) {
  int i    = blockIdx.x * 4 + (threadIdx.x >> 6);
  int lane = threadIdx.x & 63;
  int grp  = lane >> 4;   // 0..3
  int sl   = lane & 15;
  if (i >= N) return;
  int jb = rowoff[i];
  int je = rowoff[i + 1];
  const uint4e* xwq = (const uint4e*)xw;  // 16 uint4e per row
  float a0 = 0.f, a1 = 0.f, a2 = 0.f, a3 = 0.f;
  float a4 = 0.f, a5 = 0.f, a6 = 0.f, a7 = 0.f;

#define ACC8(v, o)                                                         \
  do {                                                                     \
    a0 = fmaf(__uint_as_float(((v).x & 0xffffu) << 16), (o), a0);          \
    a1 = fmaf(__uint_as_float((v).x & 0xffff0000u), (o), a1);              \
    a2 = fmaf(__uint_as_float(((v).y & 0xffffu) << 16), (o), a2);          \
    a3 = fmaf(__uint_as_float((v).y & 0xffff0000u), (o), a3);              \
    a4 = fmaf(__uint_as_float(((v).z & 0xffffu) << 16), (o), a4);          \
    a5 = fmaf(__uint_as_float((v).z & 0xffff0000u), (o), a5);              \
    a6 = fmaf(__uint_as_float(((v).w & 0xffffu) << 16), (o), a6);          \
    a7 = fmaf(__uint_as_float((v).w & 0xffff0000u), (o), a7);              \
  } while (0)

  int j = jb;
  for (; j + 8 <= je; j += 8) {
    int s0 = csr[j + grp];
    int s1 = csr[j + 4 + grp];
    float o0 = invO[s0], o1 = invO[s1];
    uint4e v0 = xwq[(size_t)s0 * 16 + sl];
    uint4e v1 = xwq[(size_t)s1 * 16 + sl];
    ACC8(v0, o0);
    ACC8(v1, o1);
  }
  for (; j < je; j += 4) {
    int e = j + grp;
    if (e < je) {
      int s = csr[e];
      float o = invO[s];
      uint4e v = xwq[(size_t)s * 16 + sl];
      ACC8(v, o);
    }
  }
#undef ACC8

  a0 += __shfl_xor(a0, 16); a0 += __shfl_xor(a0, 32);
  a1 += __shfl_xor(a1, 16); a1 += __shfl_xor(a1, 32);
  a2 += __shfl_xor(a2, 16); a2 += __shfl_xor(a2, 32);
  a3 += __shfl_xor(a3, 16); a3 += __shfl_xor(a3, 32);
  a4 += __shfl_xor(a4, 16); a4 += __shfl_xor(a4, 32);
  a5 += __shfl_xor(a5, 16); a5 += __shfl_xor(a5, 32);
  a6 += __shfl_xor(a6, 16); a6 += __shfl_xor(a6, 32);
  a7 += __shfl_xor(a7, 16); a7 += __shfl_xor(a7, 32);

  float inI = invI[i];
  int f = sl * 8;
  float4 bl = *(const float4*)&b1[f];
  float4 bh = *(const float4*)&b1[f + 4];
  float4 wl = *(const float4*)&W2[f];
  float4 wh = *(const float4*)&W2[f + 4];
  float p = fmaxf(fmaf(a0, inI, bl.x), 0.f) * wl.x
          + fmaxf(fmaf(a1, inI, bl.y), 0.f) * wl.y
          + fmaxf(fmaf(a2, inI, bl.z), 0.f) * wl.z
          + fmaxf(fmaf(a3, inI, bl.w), 0.f) * wl.w
          + fmaxf(fmaf(a4, inI, bh.x), 0.f) * wh.x
          + fmaxf(fmaf(a5, inI, bh.y), 0.f) * wh.y
          + fmaxf(fmaf(a6, inI, bh.z), 0.f) * wh.z
          + fmaxf(fmaf(a7, inI, bh.w), 0.f) * wh.w;
#pragma unroll
  for (int off = 8; off; off >>= 1) p += __shfl_xor(p, off);
  if (lane == 0) h2[i] = p * invO[i];
}

// ---------------- layer-2 gather + epilogue (4 lanes per node) ----------------
__global__ __launch_bounds__(256) void k_gather2(const float* __restrict__ h2,
                                                 const int* __restrict__ rowoff,
                                                 const int* __restrict__ csr,
                                                 const float* __restrict__ invI,
                                                 const float* __restrict__ b2,
                                                 float* __restrict__ out, int N) {
  int i = blockIdx.x * 64 + (threadIdx.x >> 2);
  int q = threadIdx.x & 3;
  if (i >= N) return;
  int jb = rowoff[i];
  int je = rowoff[i + 1];
  float s = 0.f;
  for (int j = jb + q; j < je; j += 4) s += h2[csr[j]];
  s += __shfl_xor(s, 1);
  s += __shfl_xor(s, 2);
  if (q == 0) out[i] = s * invI[i] + b2[0];
}

extern "C" void kernel_launch(void* const* d_in, const int* in_sizes, int n_in,
                              void* d_out, int out_size, void* d_ws, size_t ws_size,
                              hipStream_t stream) {
  const float* x   = (const float*)d_in[0];
  const int*   src = (const int*)d_in[1];
  const int*   dst = (const int*)d_in[2];
  const float* W1  = (const float*)d_in[3];
  const float* b1  = (const float*)d_in[4];
  const float* W2  = (const float*)d_in[5];
  const float* b2  = (const float*)d_in[6];
  int N = in_sizes[0] / NF;
  int E = in_sizes[1];
  int NB = (N + 255) >> 8;             // <= 512

  int* bucketCnt  = (int*)d_ws;                    // 512
  int* bucketCntS = bucketCnt + 512;               // 512
  unsigned short* WbT = (unsigned short*)(bucketCntS + 512);  // 128*128 bf16 (32 KB)
  int* rowoff     = (int*)(WbT + NF * NF);         // N+1 (pad to N+8)
  int* csr        = rowoff + (size_t)N + 8;        // E
  int2* region    = (int2*)(csr + (size_t)E);      // NB*CAP int2
  int* regionS    = (int*)(region + (size_t)NB * CAP);  // NB*CAP int
  float* invO     = (float*)(regionS + (size_t)NB * CAP);
  float* invI     = invO + N;
  float* h2       = invI + N;
  unsigned short* xw = (unsigned short*)(h2 + N);  // N*128 bf16
  float* out      = (float*)d_out;

  int B1 = (E + EPB - 1) / EPB;        // binA role blocks
  int B2 = (E + EPB2 - 1) / EPB2;      // binA2 role blocks
  int G  = (N + 63) / 64;              // MFMA gemm role blocks

  k_init<<<16, 256, 0, stream>>>(W1, bucketCnt, bucketCntS, rowoff, WbT, N, E);
  k_front<<<B1 + B2 + G, 256, 0, stream>>>(x, src, dst, WbT, bucketCnt, bucketCntS,
                                           region, regionS, xw, N, E, B1, B2);
  k_mid2<<<2 * NB, 256, 0, stream>>>(region, bucketCnt, regionS, bucketCntS,
                                     csr, rowoff, invI, invO, N, NB);
  k_gather_proj<<<(N + 3) / 4, 256, 0, stream>>>(xw, rowoff, csr, invI, invO, b1, W2, h2, N);
  k_gather2<<<(N + 63) / 64, 256, 0, stream>>>(h2, rowoff, csr, invI, b2, out, N);
}